// Round 1
// baseline (320.481 us; speedup 1.0000x reference)
//
#include <hip/hip_runtime.h>
#include <math.h>

// SoftSkeletonize: out = relu(img - dilate3(erode3(img))) on (2,1,192,256,256) f32.
// erode = min-pool 3x3x3, pad +inf; dilate = max-pool 3x3x3, pad -inf.
// Fused single-pass kernel: per-block (TH x TW) tile in (H,W), sliding along z
// with rotating 3-plane LDS buffers for the 2D-min (s2d) and 2D-max (t2d) stages.

#define D_ 192
#define H_ 256
#define W_ 256
#define NBATCH 2
#define TH 16
#define TW 64
#define CD 32              // z-chunk per block
#define NCHUNK (D_ / CD)   // 6

#define RAW_H (TH + 4)     // 20
#define RAW_W (TW + 4)     // 68
#define RAW_S (RAW_W + 1)  // 69 (odd stride: conflict-free)
#define S2_H  (TH + 2)     // 18
#define S2_W  (TW + 2)     // 66
#define S2_S  (S2_W + 1)   // 67
#define T2_S  (TW + 1)     // 65

__global__ __launch_bounds__(256, 4)
void soft_skel_fused(const float* __restrict__ img, float* __restrict__ out) {
    __shared__ float raw[RAW_H][RAW_S];          // current raw plane (z+2), halo 2
    __shared__ float s2d[3][S2_H][S2_S];         // 2D 3x3 min, planes z..z+2, halo 1
    __shared__ float ebuf[S2_H][S2_S];           // full erode at plane z+1, halo 1
    __shared__ float t2d[3][TH][T2_S];           // 2D 3x3 max of erode, planes z-1..z+1

    const int tid = threadIdx.x;
    const int tx  = tid & 63;       // 0..63  -> w within tile
    const int ty0 = tid >> 6;       // 0..3   -> handles rows ty0, ty0+4, ty0+8, ty0+12
    const int w0  = blockIdx.x * TW;
    const int h0  = blockIdx.y * TH;
    const int n   = blockIdx.z / NCHUNK;
    const int c   = blockIdx.z % NCHUNK;
    const int z0  = c * CD;
    const int z1  = z0 + CD;

    const float* vol  = img + (size_t)n * D_ * H_ * W_;
    float*       ovol = out + (size_t)n * D_ * H_ * W_;

    const float PINF = INFINITY;
    const float NINF = -INFINITY;

    // register pipeline of raw center values: rawA = plane z, rawB = z+1, rawC = z+2
    float rawA[4] = {0, 0, 0, 0};
    float rawB[4] = {0, 0, 0, 0};
    float rawC[4];

    int slot = 0;  // cycles 0,1,2 with the iteration
    for (int z = z0 - 4; z < z1; ++z, slot = (slot == 2 ? 0 : slot + 1)) {
        const int zz = z + 2;  // raw / s2d plane being produced this iteration

        // ---- A: stage raw plane zz into LDS (+inf outside volume = erode padding)
        if (zz >= 0 && zz < D_) {
            const float* plane = vol + (size_t)zz * H_ * W_;
            for (int i = tid; i < RAW_H * RAW_W; i += 256) {
                int r  = i / RAW_W;
                int cc = i - r * RAW_W;
                int gh = h0 - 2 + r;
                int gw = w0 - 2 + cc;
                float v = PINF;
                if (gh >= 0 && gh < H_ && gw >= 0 && gw < W_)
                    v = plane[gh * W_ + gw];
                raw[r][cc] = v;
            }
        } else {
            for (int i = tid; i < RAW_H * RAW_W; i += 256) {
                int r  = i / RAW_W;
                int cc = i - r * RAW_W;
                raw[r][cc] = PINF;
            }
        }
        __syncthreads();

        // ---- A2: capture raw centers for the output stage (plane zz)
        #pragma unroll
        for (int j = 0; j < 4; ++j)
            rawC[j] = raw[2 + ty0 + 4 * j][2 + tx];

        // ---- B: 2D 3x3 min of plane zz on the halo-1 extended tile -> s2d[slot]
        for (int i = tid; i < S2_H * S2_W; i += 256) {
            int r  = i / S2_W;
            int cc = i - r * S2_W;
            float m = raw[r][cc];
            m = fminf(m, raw[r][cc + 1]);
            m = fminf(m, raw[r][cc + 2]);
            m = fminf(m, raw[r + 1][cc]);
            m = fminf(m, raw[r + 1][cc + 1]);
            m = fminf(m, raw[r + 1][cc + 2]);
            m = fminf(m, raw[r + 2][cc]);
            m = fminf(m, raw[r + 2][cc + 1]);
            m = fminf(m, raw[r + 2][cc + 2]);
            s2d[slot][r][cc] = m;
        }
        __syncthreads();

        // ---- C: full erode at plane ze = z+1 (min over the 3 s2d slots).
        // Positions outside the image get -inf: the DILATE pads the eroded
        // image with -inf, so out-of-image erode values must not leak in.
        const int  ze   = z + 1;
        const bool zeok = (ze >= 0 && ze < D_);
        for (int i = tid; i < S2_H * S2_W; i += 256) {
            int r  = i / S2_W;
            int cc = i - r * S2_W;
            int gh = h0 - 1 + r;
            int gw = w0 - 1 + cc;
            float v = NINF;
            if (zeok && gh >= 0 && gh < H_ && gw >= 0 && gw < W_)
                v = fminf(fminf(s2d[0][r][cc], s2d[1][r][cc]), s2d[2][r][cc]);
            ebuf[r][cc] = v;
        }
        __syncthreads();

        // ---- D: 2D 3x3 max of erode plane z+1 on the core tile -> t2d[slot]
        for (int i = tid; i < TH * TW; i += 256) {
            int r  = i >> 6;
            int cc = i & 63;
            float m = ebuf[r][cc];
            m = fmaxf(m, ebuf[r][cc + 1]);
            m = fmaxf(m, ebuf[r][cc + 2]);
            m = fmaxf(m, ebuf[r + 1][cc]);
            m = fmaxf(m, ebuf[r + 1][cc + 1]);
            m = fmaxf(m, ebuf[r + 1][cc + 2]);
            m = fmaxf(m, ebuf[r + 2][cc]);
            m = fmaxf(m, ebuf[r + 2][cc + 1]);
            m = fmaxf(m, ebuf[r + 2][cc + 2]);
            t2d[slot][r][cc] = m;
        }
        __syncthreads();

        // ---- E: output plane z: opened = max over t2d planes z-1,z,z+1 (all 3 slots)
        if (z >= z0) {
            float* oplane = ovol + (size_t)z * H_ * W_;
            #pragma unroll
            for (int j = 0; j < 4; ++j) {
                int r = ty0 + 4 * j;
                float opened = fmaxf(fmaxf(t2d[0][r][tx], t2d[1][r][tx]), t2d[2][r][tx]);
                float v = rawA[j] - opened;
                oplane[(h0 + r) * W_ + (w0 + tx)] = v > 0.0f ? v : 0.0f;
            }
        }

        // shift raw register pipeline
        #pragma unroll
        for (int j = 0; j < 4; ++j) { rawA[j] = rawB[j]; rawB[j] = rawC[j]; }
    }
}

extern "C" void kernel_launch(void* const* d_in, const int* in_sizes, int n_in,
                              void* d_out, int out_size, void* d_ws, size_t ws_size,
                              hipStream_t stream) {
    const float* img = (const float*)d_in[0];
    float* out = (float*)d_out;

    dim3 grid(W_ / TW, H_ / TH, NBATCH * NCHUNK);  // (4, 16, 12) = 768 blocks
    dim3 block(256);
    soft_skel_fused<<<grid, block, 0, stream>>>(img, out);
}

// Round 2
// 194.759 us; speedup vs baseline: 1.6455x; 1.6455x over previous
//
#include <hip/hip_runtime.h>
#include <math.h>

// SoftSkeletonize: out = relu(img - dilate3(erode3(img))), (2,1,192,256,256) f32.
// erode = min-pool 3x3x3 (pad +inf), dilate = max-pool 3x3x3 (pad -inf).
//
// v2: z-direction pipelines in REGISTERS (per-position => same thread each
// plane): pmin/sprev carry the erode z-min, t2A/B/C carry the 2D-max planes,
// rwA/B/C carry raw centers. LDS holds only ONE raw plane + ONE eroded plane.
// All LDS access is b128-vectorized (8-wide thread strips), 2 barriers/plane,
// next raw plane software-prefetched into registers during compute.

#define D_ 192
#define H_ 256
#define W_ 256
#define NB 2
#define TH 32
#define TW 64
#define CD 16
#define NCHUNK (D_ / CD)      // 12

#define RAW_H (TH + 4)        // 36 rows  <-> gh = h0-2 .. h0+33
#define RAW_W (TW + 8)        // 72 cols  <-> gw = w0-4 .. w0+67
#define RAW_S 76              // padded stride (76 mod 32 = 12 -> bank spread)
#define EB_H  (TH + 2)        // 34 rows  <-> gh = h0-1 .. h0+32
#define EB_W  (TW + 8)        // 72 cols  <-> gw = w0-4 .. w0+67
#define EB_S  76

#define NRAWF4 (RAW_H * (RAW_W / 4))   // 648 float4 cells
#define NBTASK (EB_H * (EB_W / 8))     // 306 8-wide tasks

__device__ __forceinline__ float min3f(float a, float b, float c) {
    return fminf(fminf(a, b), c);
}
__device__ __forceinline__ float max3f(float a, float b, float c) {
    return fmaxf(fmaxf(a, b), c);
}

__global__ __launch_bounds__(256, 3)
void soft_skel_v2(const float* __restrict__ img, float* __restrict__ out) {
    __shared__ __align__(16) float raw[RAW_H][RAW_S];
    __shared__ __align__(16) float ebuf[EB_H][EB_S];

    const int tid = threadIdx.x;
    const int w0 = blockIdx.x * TW;
    const int h0 = blockIdx.y * TH;
    const int n  = blockIdx.z / NCHUNK;
    const int ch = blockIdx.z - n * NCHUNK;
    const int z0 = ch * CD;

    const float* vol  = img + (size_t)n * (D_ * H_ * W_);
    float*       ovol = out + (size_t)n * (D_ * H_ * W_);

    const float PINF = INFINITY;

    // ---- A-stage per-thread geometry: 3 float4 slots cover the 36x72 region
    bool a_slot[3], a_img[3];
    int  a_lds[3], a_off[3];
    #pragma unroll
    for (int k = 0; k < 3; ++k) {
        int idx = tid + 256 * k;
        bool slot = idx < NRAWF4;
        int row = idx / (RAW_W / 4);           // /18
        int cg  = idx - row * (RAW_W / 4);
        int gh = h0 - 2 + row;
        int gw = w0 - 4 + 4 * cg;
        a_slot[k] = slot;
        a_img[k]  = slot && (gh >= 0) && (gh < H_) && (gw >= 0) && (gw <= W_ - 4);
        a_off[k]  = gh * W_ + gw;
        a_lds[k]  = slot ? (row * RAW_S + 4 * cg) : 0;
    }

    // ---- B-stage task geometry (8-wide strips over 34x72 region)
    const int  r0 = tid / 9;
    const int  c0 = (tid - r0 * 9) * 8;
    const bool has1 = tid < (NBTASK - 256);    // 50 threads take a 2nd task
    const int  t1 = tid + 256;
    const int  r1 = t1 / 9;
    const int  c1 = (t1 - r1 * 9) * 8;

    // ---- D/E geometry: thread owns tile row ty, cols xx..xx+7
    const int ty = tid >> 3;
    const int xx = (tid & 7) * 8;

    // ---- register z-pipelines
    float pm0[8], sp0[8], pm1[8], sp1[8];      // erode z-min state per B task
    float t2A[8], t2B[8], t2C[8];              // 2D-max planes z-1, z, z+1
    float rwA[8], rwB[8], rwC[8];              // raw centers z, z+1, z+2
    #pragma unroll
    for (int j = 0; j < 8; ++j) {
        pm0[j] = sp0[j] = pm1[j] = sp1[j] = PINF;
        t2A[j] = t2B[j] = 0.f;
        rwA[j] = rwB[j] = 0.f;
    }

    auto prefetch = [&](int zz, float4 L[3]) {
        const bool zok = (zz >= 0) && (zz < D_);
        const float* plane = vol + (size_t)zz * (H_ * W_);
        #pragma unroll
        for (int k = 0; k < 3; ++k) {
            float4 v = make_float4(PINF, PINF, PINF, PINF);
            if (zok && a_img[k]) v = *(const float4*)(plane + a_off[k]);
            L[k] = v;
        }
    };

    // B task: 2D 3x3 min of raw -> s; e(zz-1) = min(pm, s) (masked); update pipe
    auto btask = [&](int r, int cb, float pm[8], float sp[8], bool zeok) {
        float vm[10];
        {
            const float* p0 = &raw[r][0];
            const float* p1 = &raw[r + 1][0];
            const float* p2 = &raw[r + 2][0];
            int cl = cb - 1; if (cl < 0) cl = 0;
            int cr = cb + 8; if (cr > RAW_W - 1) cr = RAW_W - 1;
            vm[0] = min3f(p0[cl], p1[cl], p2[cl]);
            vm[9] = min3f(p0[cr], p1[cr], p2[cr]);
            float4 q00 = *(const float4*)(p0 + cb);
            float4 q01 = *(const float4*)(p0 + cb + 4);
            float4 q10 = *(const float4*)(p1 + cb);
            float4 q11 = *(const float4*)(p1 + cb + 4);
            float4 q20 = *(const float4*)(p2 + cb);
            float4 q21 = *(const float4*)(p2 + cb + 4);
            vm[1] = min3f(q00.x, q10.x, q20.x);
            vm[2] = min3f(q00.y, q10.y, q20.y);
            vm[3] = min3f(q00.z, q10.z, q20.z);
            vm[4] = min3f(q00.w, q10.w, q20.w);
            vm[5] = min3f(q01.x, q11.x, q21.x);
            vm[6] = min3f(q01.y, q11.y, q21.y);
            vm[7] = min3f(q01.z, q11.z, q21.z);
            vm[8] = min3f(q01.w, q11.w, q21.w);
        }
        float s[8];
        #pragma unroll
        for (int j = 0; j < 8; ++j) s[j] = min3f(vm[j], vm[j + 1], vm[j + 2]);

        const bool rok = zeok && ((unsigned)(h0 - 1 + r) < (unsigned)H_);
        float e[8];
        #pragma unroll
        for (int j = 0; j < 8; ++j) {
            float ev = fminf(pm[j], s[j]);
            bool ok = rok && ((unsigned)(w0 - 4 + cb + j) < (unsigned)W_);
            e[j] = ok ? ev : -PINF;
            pm[j] = fminf(sp[j], s[j]);
            sp[j] = s[j];
        }
        *(float4*)&ebuf[r][cb]     = make_float4(e[0], e[1], e[2], e[3]);
        *(float4*)&ebuf[r][cb + 4] = make_float4(e[4], e[5], e[6], e[7]);
    };

    float4 L[3];
    prefetch(z0 - 2, L);
    const int zzend = z0 + CD + 1;

    for (int zz = z0 - 2; zz <= zzend; ++zz) {
        // ---- A: commit prefetched raw plane zz to LDS, start loading zz+1
        #pragma unroll
        for (int k = 0; k < 3; ++k)
            if (a_slot[k]) *(float4*)(&raw[0][0] + a_lds[k]) = L[k];
        if (zz < zzend) prefetch(zz + 1, L);
        __syncthreads();

        // ---- A2: capture raw centers of plane zz (for output zz-2 later)
        {
            float4 v0 = *(const float4*)&raw[ty + 2][xx + 4];
            float4 v1 = *(const float4*)&raw[ty + 2][xx + 8];
            rwC[0] = v0.x; rwC[1] = v0.y; rwC[2] = v0.z; rwC[3] = v0.w;
            rwC[4] = v1.x; rwC[5] = v1.y; rwC[6] = v1.z; rwC[7] = v1.w;
        }

        // ---- B: s2d(zz) + full erode e(zz-1) -> ebuf
        const int  ze   = zz - 1;
        const bool zeok = (ze >= 0) && (ze < D_);
        btask(r0, c0, pm0, sp0, zeok);
        if (has1) btask(r1, c1, pm1, sp1, zeok);
        __syncthreads();

        // ---- D: 2D 3x3 max of e(zz-1) -> t2C (registers)
        {
            float vm[10];
            const float* p0 = &ebuf[ty][0];
            const float* p1 = &ebuf[ty + 1][0];
            const float* p2 = &ebuf[ty + 2][0];
            vm[0] = max3f(p0[xx + 3], p1[xx + 3], p2[xx + 3]);
            vm[9] = max3f(p0[xx + 12], p1[xx + 12], p2[xx + 12]);
            float4 q00 = *(const float4*)(p0 + xx + 4);
            float4 q01 = *(const float4*)(p0 + xx + 8);
            float4 q10 = *(const float4*)(p1 + xx + 4);
            float4 q11 = *(const float4*)(p1 + xx + 8);
            float4 q20 = *(const float4*)(p2 + xx + 4);
            float4 q21 = *(const float4*)(p2 + xx + 8);
            vm[1] = max3f(q00.x, q10.x, q20.x);
            vm[2] = max3f(q00.y, q10.y, q20.y);
            vm[3] = max3f(q00.z, q10.z, q20.z);
            vm[4] = max3f(q00.w, q10.w, q20.w);
            vm[5] = max3f(q01.x, q11.x, q21.x);
            vm[6] = max3f(q01.y, q11.y, q21.y);
            vm[7] = max3f(q01.z, q11.z, q21.z);
            vm[8] = max3f(q01.w, q11.w, q21.w);
            #pragma unroll
            for (int j = 0; j < 8; ++j) t2C[j] = max3f(vm[j], vm[j + 1], vm[j + 2]);
        }

        // ---- E: output plane z = zz-2: relu(raw - max over t2 planes)
        if (zz >= z0 + 2) {
            const int z = zz - 2;
            float* op = ovol + ((size_t)z * H_ + (h0 + ty)) * W_ + (w0 + xx);
            float o[8];
            #pragma unroll
            for (int j = 0; j < 8; ++j) {
                float opened = max3f(t2A[j], t2B[j], t2C[j]);
                float v = rwA[j] - opened;
                o[j] = v > 0.f ? v : 0.f;
            }
            *(float4*)op       = make_float4(o[0], o[1], o[2], o[3]);
            *(float4*)(op + 4) = make_float4(o[4], o[5], o[6], o[7]);
        }

        // ---- shift register pipelines
        #pragma unroll
        for (int j = 0; j < 8; ++j) {
            t2A[j] = t2B[j]; t2B[j] = t2C[j];
            rwA[j] = rwB[j]; rwB[j] = rwC[j];
        }
    }
}

extern "C" void kernel_launch(void* const* d_in, const int* in_sizes, int n_in,
                              void* d_out, int out_size, void* d_ws, size_t ws_size,
                              hipStream_t stream) {
    const float* img = (const float*)d_in[0];
    float* out = (float*)d_out;

    dim3 grid(W_ / TW, H_ / TH, NB * NCHUNK);   // (4, 8, 24) = 768 blocks
    dim3 block(256);
    soft_skel_v2<<<grid, block, 0, stream>>>(img, out);
}